// Round 1
// baseline (439.047 us; speedup 1.0000x reference)
//
#include <hip/hip_runtime.h>
#include <hip/hip_bf16.h>

// Classifier_69818988363910:
//   F = mean_pool_J30(relu(x @ W1^T))            [2000, 2048]
//   logits = F @ (Wlin[:, :2048]+Wlin[:, 2048:])^T  [2000, 1000]
// (y, W2 are dead per the reference's own bug; features2 == features)

typedef __attribute__((ext_vector_type(4))) float f32x4;
typedef __attribute__((ext_vector_type(8))) short short8;

#define BM 128
#define BN 128
#define BK 64

__device__ __forceinline__ unsigned short f2bf(float f) {
  // round-to-nearest-even f32 -> bf16 (inputs are finite; no NaN handling)
  unsigned int u = __float_as_uint(f);
  unsigned int r = (u + 0x7fffu + ((u >> 16) & 1u)) >> 16;
  return (unsigned short)r;
}

__device__ __forceinline__ unsigned long long pack4(f32x4 v) {
  return (unsigned long long)f2bf(v.x)
       | ((unsigned long long)f2bf(v.y) << 16)
       | ((unsigned long long)f2bf(v.z) << 32)
       | ((unsigned long long)f2bf(v.w) << 48);
}

__device__ __forceinline__ void gload_lds16(const unsigned short* gp, unsigned short* lp) {
  __builtin_amdgcn_global_load_lds((const __attribute__((address_space(1))) void*)gp,
                                   (__attribute__((address_space(3))) void*)lp, 16, 0, 0);
}

__global__ void cvt_f32_bf16(const float* __restrict__ src,
                             unsigned short* __restrict__ dst, int n4) {
  int i = blockIdx.x * 256 + threadIdx.x;
  if (i >= n4) return;
  f32x4 v = *(const f32x4*)(src + (size_t)i * 4);
  *(unsigned long long*)(dst + (size_t)i * 4) = pack4(v);
}

// Wsum[c][f] = bf16(Wlin[c][f] + Wlin[c][2048+f]),  c<1000, f<2048
__global__ void prep_wsum(const float* __restrict__ wlin,
                          unsigned short* __restrict__ dst) {
  int i = blockIdx.x * 256 + threadIdx.x;  // over 1000*2048/4 = 512000
  if (i >= 1000 * 512) return;
  int c = i >> 9, f4 = i & 511;
  const float* p0 = wlin + (size_t)c * 4096 + f4 * 4;
  f32x4 a = *(const f32x4*)p0;
  f32x4 b = *(const f32x4*)(p0 + 2048);
  f32x4 s = a + b;
  *(unsigned long long*)(dst + (size_t)c * 2048 + f4 * 4) = pack4(s);
}

// C = A @ B^T, A:[Mv][K], B:[Nv][K], both K-contiguous.
// MODE 0: A,B f32, reg-staged + convert (padded LDS); pool epilogue -> bf16 features
// MODE 1: A,B bf16, global_load_lds staging (linear LDS); pool epilogue
// MODE 2: A,B bf16, global_load_lds staging; plain guarded f32 store
template<int MODE>
__global__ __launch_bounds__(256, 2)
void gemm_bt(const void* __restrict__ Ap, const void* __restrict__ Bp,
             void* __restrict__ Cp, int Mv, int Nv, int K, int mstep) {
  constexpr int LDK = (MODE == 0) ? 72 : 64;  // +16B pad in reg-staged mode
  __shared__ __align__(16) unsigned short smem[2 * BM * LDK];
  unsigned short* As = smem;
  unsigned short* Bs = smem + BM * LDK;
  float* Cs = (float*)smem;  // epilogue reuse (32KB <= smem size)

  const int tid = threadIdx.x;
  const int lane = tid & 63;
  const int w = tid >> 6;
  const int wr = w >> 1, wc = w & 1;
  const int bm0 = blockIdx.y * mstep;
  const int bn0 = blockIdx.x * BN;

  f32x4 acc[4][4];
#pragma unroll
  for (int i = 0; i < 4; ++i)
#pragma unroll
    for (int j = 0; j < 4; ++j) acc[i][j] = (f32x4){0.f, 0.f, 0.f, 0.f};

  const int fr = lane & 15;
  const int ko = (lane >> 4) * 8;

  for (int kt = 0; kt < K; kt += BK) {
    __syncthreads();
    if constexpr (MODE == 0) {
      const float* A = (const float*)Ap;
      const float* B = (const float*)Bp;
      const int r0 = tid >> 4, kq = tid & 15;
#pragma unroll
      for (int i = 0; i < 8; ++i) {
        int row = i * 16 + r0;
        {
          int gm = bm0 + row;
          f32x4 v = {0.f, 0.f, 0.f, 0.f};
          if (gm < Mv) v = *(const f32x4*)(A + (size_t)gm * K + kt + kq * 4);
          *(unsigned long long*)(As + row * LDK + kq * 4) = pack4(v);
        }
        {
          int gn = bn0 + row;
          f32x4 v = {0.f, 0.f, 0.f, 0.f};
          if (gn < Nv) v = *(const f32x4*)(B + (size_t)gn * K + kt + kq * 4);
          *(unsigned long long*)(Bs + row * LDK + kq * 4) = pack4(v);
        }
      }
    } else {
      const unsigned short* A = (const unsigned short*)Ap;
      const unsigned short* B = (const unsigned short*)Bp;
      const int rsub = lane >> 3;
      const int k8 = (lane & 7) * 8;
#pragma unroll
      for (int j = 0; j < 4; ++j) {
        int g = w * 4 + j;          // 16 groups of 8 rows
        int row = g * 8 + rsub;
        int gm = bm0 + row; if (gm >= Mv) gm = Mv - 1;   // clamp: safe, result discarded
        gload_lds16(A + (size_t)gm * K + kt + k8, As + g * 512);
        int gn = bn0 + row; if (gn >= Nv) gn = Nv - 1;
        gload_lds16(B + (size_t)gn * K + kt + k8, Bs + g * 512);
      }
    }
    __syncthreads();
#pragma unroll
    for (int kk = 0; kk < 2; ++kk) {
      short8 af[4], bfr[4];
#pragma unroll
      for (int i = 0; i < 4; ++i)
        af[i] = *(const short8*)(As + (wr * 64 + i * 16 + fr) * LDK + kk * 32 + ko);
#pragma unroll
      for (int i = 0; i < 4; ++i)
        bfr[i] = *(const short8*)(Bs + (wc * 64 + i * 16 + fr) * LDK + kk * 32 + ko);
#pragma unroll
      for (int i = 0; i < 4; ++i)
#pragma unroll
        for (int j = 0; j < 4; ++j)
          acc[i][j] = __builtin_amdgcn_mfma_f32_16x16x32_bf16(af[i], bfr[j], acc[i][j], 0, 0, 0);
    }
  }
  __syncthreads();

  if constexpr (MODE != 2) {
    // relu + mean over J=30 row-segments; tile rows 0..119 = 4 segments, 120..127 discarded
    unsigned short* feat = (unsigned short*)Cp;  // [2000][2048] bf16
    const int cr0 = (lane >> 4) * 4;
#pragma unroll
    for (int half = 0; half < 2; ++half) {
      if (wc == half) {
#pragma unroll
        for (int i = 0; i < 4; ++i)
#pragma unroll
          for (int j = 0; j < 4; ++j)
#pragma unroll
            for (int r = 0; r < 4; ++r)
              Cs[(wr * 64 + i * 16 + cr0 + r) * 64 + j * 16 + fr] =
                  fmaxf(acc[i][j][r], 0.f);
      }
      __syncthreads();
      {
        int col = tid & 63;
        int s = tid >> 6;  // 0..3
        float sum = 0.f;
#pragma unroll
        for (int r = 0; r < 30; ++r) sum += Cs[(s * 30 + r) * 64 + col];
        int gseg = blockIdx.y * 4 + s;
        int gcol = bn0 + half * 64 + col;
        feat[(size_t)gseg * 2048 + gcol] = f2bf(sum * (1.f / 30.f));
      }
      __syncthreads();
    }
  } else {
    float* out = (float*)Cp;  // [Mv][Nv] f32, row-major
    const int cr0 = (lane >> 4) * 4;
#pragma unroll
    for (int i = 0; i < 4; ++i)
#pragma unroll
      for (int j = 0; j < 4; ++j)
#pragma unroll
        for (int r = 0; r < 4; ++r) {
          int gm = bm0 + wr * 64 + i * 16 + cr0 + r;
          int gn = bn0 + wc * 64 + j * 16 + fr;
          if (gm < Mv && gn < Nv) out[(size_t)gm * Nv + gn] = acc[i][j][r];
        }
  }
}

extern "C" void kernel_launch(void* const* d_in, const int* in_sizes, int n_in,
                              void* d_out, int out_size, void* d_ws, size_t ws_size,
                              hipStream_t stream) {
  const float* x    = (const float*)d_in[0];
  const float* W1   = (const float*)d_in[2];
  const float* Wlin = (const float*)d_in[4];
  float* out = (float*)d_out;

  const int T = 60000, DIN = 1024, E = 2048, C = 1000, S = 2000;
  char* ws = (char*)d_ws;
  const size_t off_feat = 0;                        // S*E*2   = 8,192,000
  const size_t off_wsum = (size_t)S * E * 2;        // C*E*2   = 4,096,000
  const size_t off_w1b  = off_wsum + (size_t)C * E * 2;   // E*DIN*2 = 4,194,304
  const size_t off_xb   = off_w1b + (size_t)E * DIN * 2;  // T*DIN*2 = 122,880,000
  const size_t need_full = off_xb + (size_t)T * DIN * 2;  // ~139.4 MB

  unsigned short* feat = (unsigned short*)(ws + off_feat);
  unsigned short* wsum = (unsigned short*)(ws + off_wsum);

  prep_wsum<<<dim3((C * E / 4 + 255) / 256), dim3(256), 0, stream>>>(Wlin, wsum);

  if (ws_size >= need_full) {
    unsigned short* w1b = (unsigned short*)(ws + off_w1b);
    unsigned short* xb  = (unsigned short*)(ws + off_xb);
    int nx4 = T * DIN / 4;
    cvt_f32_bf16<<<dim3((nx4 + 255) / 256), dim3(256), 0, stream>>>(x, xb, nx4);
    int nw4 = E * DIN / 4;
    cvt_f32_bf16<<<dim3((nw4 + 255) / 256), dim3(256), 0, stream>>>(W1, w1b, nw4);
    // 500 M-blocks (120 valid rows each = 4 segments), 16 N-blocks
    gemm_bt<1><<<dim3(16, 500), dim3(256), 0, stream>>>(xb, w1b, feat, T, E, DIN, 120);
  } else {
    gemm_bt<0><<<dim3(16, 500), dim3(256), 0, stream>>>(x, W1, feat, T, E, DIN, 120);
  }

  // logits = feat @ wsum^T   [2000,1000] f32
  gemm_bt<2><<<dim3(8, 16), dim3(256), 0, stream>>>(feat, wsum, out, S, C, E, 128);
}

// Round 2
// 419.913 us; speedup vs baseline: 1.0456x; 1.0456x over previous
//
#include <hip/hip_runtime.h>
#include <hip/hip_bf16.h>

// Classifier_69818988363910:
//   F = mean_pool_J30(relu(x @ W1^T))                [2000, 2048]
//   logits = F @ (Wlin[:, :2048]+Wlin[:, 2048:])^T   [2000, 1000]
// (y, W2 are dead per the reference's own bug; features2 == features)

typedef __attribute__((ext_vector_type(4))) float f32x4;
typedef __attribute__((ext_vector_type(8))) short short8;

__device__ __forceinline__ unsigned short f2bf(float f) {
  unsigned int u = __float_as_uint(f);
  unsigned int r = (u + 0x7fffu + ((u >> 16) & 1u)) >> 16;
  return (unsigned short)r;
}

__device__ __forceinline__ unsigned long long pack4(f32x4 v) {
  return (unsigned long long)f2bf(v.x)
       | ((unsigned long long)f2bf(v.y) << 16)
       | ((unsigned long long)f2bf(v.z) << 32)
       | ((unsigned long long)f2bf(v.w) << 48);
}

__device__ __forceinline__ void gload_lds16(const unsigned short* gp, unsigned short* lp) {
  __builtin_amdgcn_global_load_lds((const __attribute__((address_space(1))) void*)gp,
                                   (__attribute__((address_space(3))) void*)lp, 16, 0, 0);
}

__global__ void cvt_f32_bf16(const float* __restrict__ src,
                             unsigned short* __restrict__ dst, int n4) {
  int i = blockIdx.x * 256 + threadIdx.x;
  if (i >= n4) return;
  f32x4 v = *(const f32x4*)(src + (size_t)i * 4);
  *(unsigned long long*)(dst + (size_t)i * 4) = pack4(v);
}

__global__ void prep_wsum(const float* __restrict__ wlin,
                          unsigned short* __restrict__ dst) {
  int i = blockIdx.x * 256 + threadIdx.x;
  if (i >= 1000 * 512) return;
  int c = i >> 9, f4 = i & 511;
  const float* p0 = wlin + (size_t)c * 4096 + f4 * 4;
  f32x4 a = *(const f32x4*)p0;
  f32x4 b = *(const f32x4*)(p0 + 2048);
  f32x4 s = a + b;
  *(unsigned long long*)(dst + (size_t)c * 2048 + f4 * 4) = pack4(s);
}

// ---------------------------------------------------------------------------
// GEMM1: 256x256 tile, BK=32, 4-deep LDS ring, counted-vmcnt pipeline.
// A:[Mv][K] bf16, B:[2048][K] bf16. Epilogue: relu + mean over J=30 row
// segments (8 segments from rows 0..239; rows 240..255 discarded).
// 512 threads = 8 waves arranged 2(M) x 4(N); per-wave output 128x64.
// ---------------------------------------------------------------------------
#define WAITV(n) asm volatile("s_waitcnt vmcnt(" #n ")" ::: "memory")
#define CFENCE() asm volatile("" ::: "memory")

__global__ __launch_bounds__(512, 2)
void gemm256_pool(const unsigned short* __restrict__ A,
                  const unsigned short* __restrict__ B,
                  unsigned short* __restrict__ feat,
                  int Mv, int K) {
  // 4 ring buffers x (A 256x32 + B 256x32) bf16 = 4 x 32 KB = 128 KB
  __shared__ __align__(16) unsigned short smem[4 * 16384];

  const int tid = threadIdx.x;
  const int lane = tid & 63;
  const int w = tid >> 6;          // 0..7
  const int wr = w >> 2;           // 0..1  (M half)
  const int wc = w & 3;            // 0..3  (N quarter)
  const int bm0 = blockIdx.y * 240;
  const int bn0 = blockIdx.x * 256;
  const int NT = K >> 5;           // K-tiles of 32

  // ---- staging addresses (per thread, constant across K loop) ----
  // load li in {0,1}: rows w*32 + li*16 + (lane>>2), k-slot (lane&3)*8
  const int rsub = lane >> 2;
  const int kslot = (lane & 3) * 8;
  int rA0 = bm0 + w * 32 + 0 + rsub;  if (rA0 >= Mv) rA0 = Mv - 1;
  int rA1 = bm0 + w * 32 + 16 + rsub; if (rA1 >= Mv) rA1 = Mv - 1;
  const int rB0 = bn0 + w * 32 + 0 + rsub;    // N=2048 divisible by 256
  const int rB1 = bn0 + w * 32 + 16 + rsub;
  const unsigned short* gA0 = A + (size_t)rA0 * K + kslot;
  const unsigned short* gA1 = A + (size_t)rA1 * K + kslot;
  const unsigned short* gB0 = B + (size_t)rB0 * K + kslot;
  const unsigned short* gB1 = B + (size_t)rB1 * K + kslot;
  // LDS dest (wave-uniform base; HW adds lane*16B)
  unsigned short* ldA0 = smem + w * 1024;
  unsigned short* ldA1 = smem + w * 1024 + 512;
  unsigned short* ldB0 = smem + 8192 + w * 1024;
  unsigned short* ldB1 = smem + 8192 + w * 1024 + 512;

#define STAGE(tt)                                                        \
  do {                                                                   \
    const int _b = ((tt) & 3) << 14;                                     \
    const size_t _k = (size_t)(tt) * 32;                                 \
    gload_lds16(gA0 + _k, ldA0 + _b);                                    \
    gload_lds16(gA1 + _k, ldA1 + _b);                                    \
    gload_lds16(gB0 + _k, ldB0 + _b);                                    \
    gload_lds16(gB1 + _k, ldB1 + _b);                                    \
  } while (0)

  f32x4 acc[8][4];
#pragma unroll
  for (int i = 0; i < 8; ++i)
#pragma unroll
    for (int j = 0; j < 4; ++j) acc[i][j] = (f32x4){0.f, 0.f, 0.f, 0.f};

  // fragment read offsets (shorts), constant per thread
  const int fr = lane & 15;
  const int q8 = (lane >> 4) * 8;
  const int aoff = wr * 4096 + fr * 32 + q8;          // + i*512
  const int boff = 8192 + (wc * 64 + fr) * 32 + q8;   // + j*512

  // ---- prologue: 3 tiles in flight ----
  STAGE(0); STAGE(1); STAGE(2);

  for (int t = 0; t < NT; ++t) {
    if (t + 3 < NT) {
      STAGE(t + 3);
      WAITV(12);               // tile t fully landed; 3 tiles still in flight
    } else if (t + 3 == NT) {
      WAITV(8);
    } else if (t + 2 == NT) {
      WAITV(4);
    } else {
      WAITV(0);
    }
    __builtin_amdgcn_s_barrier();
    CFENCE();

    const int bb = (t & 3) << 14;
    short8 af[8], bf[4];
#pragma unroll
    for (int i = 0; i < 8; ++i)
      af[i] = *(const short8*)(smem + bb + aoff + i * 512);
#pragma unroll
    for (int j = 0; j < 4; ++j)
      bf[j] = *(const short8*)(smem + bb + boff + j * 512);

    __builtin_amdgcn_s_setprio(1);
#pragma unroll
    for (int i = 0; i < 8; ++i)
#pragma unroll
      for (int j = 0; j < 4; ++j)
        acc[i][j] = __builtin_amdgcn_mfma_f32_16x16x32_bf16(af[i], bf[j], acc[i][j], 0, 0, 0);
    __builtin_amdgcn_s_setprio(0);

    CFENCE();
    __builtin_amdgcn_s_barrier();   // protect buf[t&3] from next iter's STAGE
  }

  // ---- epilogue: relu + J=30 mean pool, via f32 [256][65] LDS panel ----
  float* panel = (float*)smem;      // 256*65*4 = 66560 B <= 128 KB
  const int q4 = (lane >> 4) * 4;
#pragma unroll 1
  for (int c = 0; c < 4; ++c) {
    if (wc == c) {
#pragma unroll
      for (int i = 0; i < 8; ++i)
#pragma unroll
        for (int j = 0; j < 4; ++j)
#pragma unroll
          for (int r = 0; r < 4; ++r)
            panel[(wr * 128 + i * 16 + q4 + r) * 65 + j * 16 + fr] =
                fmaxf(acc[i][j][r], 0.f);
    }
    __builtin_amdgcn_s_barrier();
    CFENCE();
    {
      int col = tid & 63;
      int s = tid >> 6;             // 0..7 segments
      float sum = 0.f;
#pragma unroll
      for (int r = 0; r < 30; ++r) sum += panel[(s * 30 + r) * 65 + col];
      int gseg = blockIdx.y * 8 + s;
      int gcol = bn0 + c * 64 + col;
      feat[(size_t)gseg * 2048 + gcol] = f2bf(sum * (1.f / 30.f));
    }
    CFENCE();
    __builtin_amdgcn_s_barrier();
  }
#undef STAGE
}

// ---------------------------------------------------------------------------
// Old 128x128 kernel kept for GEMM2 (MODE 2) and the no-workspace fallback
// (MODE 0 with pooled epilogue).
// ---------------------------------------------------------------------------
#define BM 128
#define BN 128
#define BK 64

template<int MODE>
__global__ __launch_bounds__(256, 2)
void gemm_bt(const void* __restrict__ Ap, const void* __restrict__ Bp,
             void* __restrict__ Cp, int Mv, int Nv, int K, int mstep) {
  constexpr int LDK = (MODE == 0) ? 72 : 64;
  __shared__ __align__(16) unsigned short smem[2 * BM * LDK];
  unsigned short* As = smem;
  unsigned short* Bs = smem + BM * LDK;
  float* Cs = (float*)smem;

  const int tid = threadIdx.x;
  const int lane = tid & 63;
  const int w = tid >> 6;
  const int wr = w >> 1, wc = w & 1;
  const int bm0 = blockIdx.y * mstep;
  const int bn0 = blockIdx.x * BN;

  f32x4 acc[4][4];
#pragma unroll
  for (int i = 0; i < 4; ++i)
#pragma unroll
    for (int j = 0; j < 4; ++j) acc[i][j] = (f32x4){0.f, 0.f, 0.f, 0.f};

  const int fr = lane & 15;
  const int ko = (lane >> 4) * 8;

  for (int kt = 0; kt < K; kt += BK) {
    __syncthreads();
    if constexpr (MODE == 0) {
      const float* A = (const float*)Ap;
      const float* B = (const float*)Bp;
      const int r0 = tid >> 4, kq = tid & 15;
#pragma unroll
      for (int i = 0; i < 8; ++i) {
        int row = i * 16 + r0;
        {
          int gm = bm0 + row;
          f32x4 v = {0.f, 0.f, 0.f, 0.f};
          if (gm < Mv) v = *(const f32x4*)(A + (size_t)gm * K + kt + kq * 4);
          *(unsigned long long*)(As + row * LDK + kq * 4) = pack4(v);
        }
        {
          int gn = bn0 + row;
          f32x4 v = {0.f, 0.f, 0.f, 0.f};
          if (gn < Nv) v = *(const f32x4*)(B + (size_t)gn * K + kt + kq * 4);
          *(unsigned long long*)(Bs + row * LDK + kq * 4) = pack4(v);
        }
      }
    } else {
      const unsigned short* A = (const unsigned short*)Ap;
      const unsigned short* B = (const unsigned short*)Bp;
      const int rsub = lane >> 3;
      const int k8 = (lane & 7) * 8;
#pragma unroll
      for (int j = 0; j < 4; ++j) {
        int g = w * 4 + j;
        int row = g * 8 + rsub;
        int gm = bm0 + row; if (gm >= Mv) gm = Mv - 1;
        gload_lds16(A + (size_t)gm * K + kt + k8, As + g * 512);
        int gn = bn0 + row; if (gn >= Nv) gn = Nv - 1;
        gload_lds16(B + (size_t)gn * K + kt + k8, Bs + g * 512);
      }
    }
    __syncthreads();
#pragma unroll
    for (int kk = 0; kk < 2; ++kk) {
      short8 af[4], bfr[4];
#pragma unroll
      for (int i = 0; i < 4; ++i)
        af[i] = *(const short8*)(As + (wr * 64 + i * 16 + fr) * LDK + kk * 32 + ko);
#pragma unroll
      for (int i = 0; i < 4; ++i)
        bfr[i] = *(const short8*)(Bs + (wc * 64 + i * 16 + fr) * LDK + kk * 32 + ko);
#pragma unroll
      for (int i = 0; i < 4; ++i)
#pragma unroll
        for (int j = 0; j < 4; ++j)
          acc[i][j] = __builtin_amdgcn_mfma_f32_16x16x32_bf16(af[i], bfr[j], acc[i][j], 0, 0, 0);
    }
  }
  __syncthreads();

  if constexpr (MODE != 2) {
    unsigned short* feat = (unsigned short*)Cp;
    const int cr0 = (lane >> 4) * 4;
#pragma unroll
    for (int half = 0; half < 2; ++half) {
      if (wc == half) {
#pragma unroll
        for (int i = 0; i < 4; ++i)
#pragma unroll
          for (int j = 0; j < 4; ++j)
#pragma unroll
            for (int r = 0; r < 4; ++r)
              Cs[(wr * 64 + i * 16 + cr0 + r) * 64 + j * 16 + fr] =
                  fmaxf(acc[i][j][r], 0.f);
      }
      __syncthreads();
      {
        int col = tid & 63;
        int s = tid >> 6;
        float sum = 0.f;
#pragma unroll
        for (int r = 0; r < 30; ++r) sum += Cs[(s * 30 + r) * 64 + col];
        int gseg = blockIdx.y * 4 + s;
        int gcol = bn0 + half * 64 + col;
        feat[(size_t)gseg * 2048 + gcol] = f2bf(sum * (1.f / 30.f));
      }
      __syncthreads();
    }
  } else {
    float* out = (float*)Cp;
    const int cr0 = (lane >> 4) * 4;
#pragma unroll
    for (int i = 0; i < 4; ++i)
#pragma unroll
      for (int j = 0; j < 4; ++j)
#pragma unroll
        for (int r = 0; r < 4; ++r) {
          int gm = bm0 + wr * 64 + i * 16 + cr0 + r;
          int gn = bn0 + wc * 64 + j * 16 + fr;
          if (gm < Mv && gn < Nv) out[(size_t)gm * Nv + gn] = acc[i][j][r];
        }
  }
}

extern "C" void kernel_launch(void* const* d_in, const int* in_sizes, int n_in,
                              void* d_out, int out_size, void* d_ws, size_t ws_size,
                              hipStream_t stream) {
  const float* x    = (const float*)d_in[0];
  const float* W1   = (const float*)d_in[2];
  const float* Wlin = (const float*)d_in[4];
  float* out = (float*)d_out;

  const int T = 60000, DIN = 1024, E = 2048, C = 1000, S = 2000;
  char* ws = (char*)d_ws;
  const size_t off_feat = 0;
  const size_t off_wsum = (size_t)S * E * 2;
  const size_t off_w1b  = off_wsum + (size_t)C * E * 2;
  const size_t off_xb   = off_w1b + (size_t)E * DIN * 2;
  const size_t need_full = off_xb + (size_t)T * DIN * 2;   // ~139.4 MB

  unsigned short* feat = (unsigned short*)(ws + off_feat);
  unsigned short* wsum = (unsigned short*)(ws + off_wsum);

  prep_wsum<<<dim3((C * E / 4 + 255) / 256), dim3(256), 0, stream>>>(Wlin, wsum);

  if (ws_size >= need_full) {
    unsigned short* w1b = (unsigned short*)(ws + off_w1b);
    unsigned short* xb  = (unsigned short*)(ws + off_xb);
    int nx4 = T * DIN / 4;
    cvt_f32_bf16<<<dim3((nx4 + 255) / 256), dim3(256), 0, stream>>>(x, xb, nx4);
    int nw4 = E * DIN / 4;
    cvt_f32_bf16<<<dim3((nw4 + 255) / 256), dim3(256), 0, stream>>>(W1, w1b, nw4);
    // 250 M-blocks (240 valid rows = 8 segments each) x 8 N-blocks
    gemm256_pool<<<dim3(8, 250), dim3(512), 0, stream>>>(xb, w1b, feat, T, DIN);
  } else {
    gemm_bt<0><<<dim3(16, 500), dim3(256), 0, stream>>>(x, W1, feat, T, E, DIN, 120);
  }

  // logits = feat @ wsum^T   [2000,1000] f32
  gemm_bt<2><<<dim3(8, 16), dim3(256), 0, stream>>>(feat, wsum, out, S, C, E, 128);
}

// Round 3
// 400.214 us; speedup vs baseline: 1.0970x; 1.0492x over previous
//
#include <hip/hip_runtime.h>
#include <hip/hip_bf16.h>

// Classifier_69818988363910:
//   F = mean_pool_J30(relu(x @ W1^T))                [2000, 2048]
//   logits = F @ (Wlin[:, :2048]+Wlin[:, 2048:])^T   [2000, 1000]
// (y, W2 are dead per the reference's own bug; features2 == features)

typedef __attribute__((ext_vector_type(4))) float f32x4;
typedef __attribute__((ext_vector_type(8))) short short8;

__device__ __forceinline__ unsigned short f2bf(float f) {
  unsigned int u = __float_as_uint(f);
  unsigned int r = (u + 0x7fffu + ((u >> 16) & 1u)) >> 16;
  return (unsigned short)r;
}

__device__ __forceinline__ unsigned long long pack4(f32x4 v) {
  return (unsigned long long)f2bf(v.x)
       | ((unsigned long long)f2bf(v.y) << 16)
       | ((unsigned long long)f2bf(v.z) << 32)
       | ((unsigned long long)f2bf(v.w) << 48);
}

__device__ __forceinline__ void gload_lds16(const unsigned short* gp, unsigned short* lp) {
  __builtin_amdgcn_global_load_lds((const __attribute__((address_space(1))) void*)gp,
                                   (__attribute__((address_space(3))) void*)lp, 16, 0, 0);
}

__global__ void cvt_f32_bf16(const float* __restrict__ src,
                             unsigned short* __restrict__ dst, int n4) {
  int i = blockIdx.x * 256 + threadIdx.x;
  if (i >= n4) return;
  f32x4 v = *(const f32x4*)(src + (size_t)i * 4);
  *(unsigned long long*)(dst + (size_t)i * 4) = pack4(v);
}

__global__ void prep_wsum(const float* __restrict__ wlin,
                          unsigned short* __restrict__ dst) {
  int i = blockIdx.x * 256 + threadIdx.x;
  if (i >= 1000 * 512) return;
  int c = i >> 9, f4 = i & 511;
  const float* p0 = wlin + (size_t)c * 4096 + f4 * 4;
  f32x4 a = *(const f32x4*)p0;
  f32x4 b = *(const f32x4*)(p0 + 2048);
  f32x4 s = a + b;
  *(unsigned long long*)(dst + (size_t)c * 2048 + f4 * 4) = pack4(s);
}

// ---------------------------------------------------------------------------
// GEMM1: 256x256 tile, BK=32, 4-deep LDS ring, counted-vmcnt pipeline,
// XOR-swizzled LDS (chunk ^= (row>>1)&3; pre-swizzled global source since
// global_load_lds writes linearly — rule #21 both-sides-or-neither).
// ---------------------------------------------------------------------------
#define WAITV(n) asm volatile("s_waitcnt vmcnt(" #n ")" ::: "memory")
#define CFENCE() asm volatile("" ::: "memory")

__global__ __launch_bounds__(512, 2)
void gemm256_pool(const unsigned short* __restrict__ A,
                  const unsigned short* __restrict__ B,
                  unsigned short* __restrict__ feat,
                  int Mv, int K) {
  __shared__ __align__(16) unsigned short smem[4 * 16384];  // 128 KB ring

  const int tid = threadIdx.x;
  const int lane = tid & 63;
  const int w = tid >> 6;          // 0..7
  const int wr = w >> 2;           // 0..1  (M half)
  const int wc = w & 3;            // 0..3  (N quarter)
  const int bm0 = blockIdx.y * 240;
  const int bn0 = blockIdx.x * 256;
  const int NT = K >> 5;           // K-tiles of 32

  // ---- staging: lane's 16B lands at physical chunk (lane&3) of row
  // (base + lane>>2). Pre-swizzle global k so logical chunk
  // c_log = c_phys ^ ((row>>1)&3) = (lane&3) ^ ((lane>>3)&3). ----
  const int rsub = lane >> 2;
  const int kslot = (((lane & 3) ^ ((lane >> 3) & 3)) * 8);
  int rA0 = bm0 + w * 32 + 0 + rsub;  if (rA0 >= Mv) rA0 = Mv - 1;
  int rA1 = bm0 + w * 32 + 16 + rsub; if (rA1 >= Mv) rA1 = Mv - 1;
  const int rB0 = bn0 + w * 32 + 0 + rsub;
  const int rB1 = bn0 + w * 32 + 16 + rsub;
  const unsigned short* gA0 = A + (size_t)rA0 * K + kslot;
  const unsigned short* gA1 = A + (size_t)rA1 * K + kslot;
  const unsigned short* gB0 = B + (size_t)rB0 * K + kslot;
  const unsigned short* gB1 = B + (size_t)rB1 * K + kslot;
  unsigned short* ldA0 = smem + w * 1024;
  unsigned short* ldA1 = smem + w * 1024 + 512;
  unsigned short* ldB0 = smem + 8192 + w * 1024;
  unsigned short* ldB1 = smem + 8192 + w * 1024 + 512;

#define STAGE(tt)                                                        \
  do {                                                                   \
    const int _b = ((tt) & 3) << 14;                                     \
    const size_t _k = (size_t)(tt) * 32;                                 \
    gload_lds16(gA0 + _k, ldA0 + _b);                                    \
    gload_lds16(gA1 + _k, ldA1 + _b);                                    \
    gload_lds16(gB0 + _k, ldB0 + _b);                                    \
    gload_lds16(gB1 + _k, ldB1 + _b);                                    \
  } while (0)

  f32x4 acc[8][4];
#pragma unroll
  for (int i = 0; i < 8; ++i)
#pragma unroll
    for (int j = 0; j < 4; ++j) acc[i][j] = (f32x4){0.f, 0.f, 0.f, 0.f};

  // fragment reads: row fr (+16*i), chunk q=lane>>4 -> swizzled q^((fr>>1)&3)
  const int fr = lane & 15;
  const int qs8 = (((lane >> 4) ^ ((fr >> 1) & 3)) * 8);
  const int aoff = wr * 4096 + fr * 32 + qs8;          // + i*512
  const int boff = 8192 + (wc * 64 + fr) * 32 + qs8;   // + j*512

  STAGE(0); STAGE(1); STAGE(2);

  for (int t = 0; t < NT; ++t) {
    if (t + 3 < NT) {
      STAGE(t + 3);
      WAITV(12);
    } else if (t + 3 == NT) {
      WAITV(8);
    } else if (t + 2 == NT) {
      WAITV(4);
    } else {
      WAITV(0);
    }
    __builtin_amdgcn_s_barrier();
    CFENCE();

    const int bb = (t & 3) << 14;
    short8 af[8], bf[4];
#pragma unroll
    for (int i = 0; i < 8; ++i)
      af[i] = *(const short8*)(smem + bb + aoff + i * 512);
#pragma unroll
    for (int j = 0; j < 4; ++j)
      bf[j] = *(const short8*)(smem + bb + boff + j * 512);

    __builtin_amdgcn_s_setprio(1);
#pragma unroll
    for (int i = 0; i < 8; ++i)
#pragma unroll
      for (int j = 0; j < 4; ++j)
        acc[i][j] = __builtin_amdgcn_mfma_f32_16x16x32_bf16(af[i], bf[j], acc[i][j], 0, 0, 0);
    __builtin_amdgcn_s_setprio(0);

    CFENCE();
    __builtin_amdgcn_s_barrier();
  }

  // ---- epilogue: relu + J=30 mean pool via padded f32 [256][65] panel ----
  float* panel = (float*)smem;
  const int q4 = (lane >> 4) * 4;
#pragma unroll 1
  for (int c = 0; c < 4; ++c) {
    if (wc == c) {
#pragma unroll
      for (int i = 0; i < 8; ++i)
#pragma unroll
        for (int j = 0; j < 4; ++j)
#pragma unroll
          for (int r = 0; r < 4; ++r)
            panel[(wr * 128 + i * 16 + q4 + r) * 65 + j * 16 + fr] =
                fmaxf(acc[i][j][r], 0.f);
    }
    __builtin_amdgcn_s_barrier();
    CFENCE();
    {
      int col = tid & 63;
      int s = tid >> 6;
      float sum = 0.f;
#pragma unroll
      for (int r = 0; r < 30; ++r) sum += panel[(s * 30 + r) * 65 + col];
      int gseg = blockIdx.y * 8 + s;
      int gcol = bn0 + c * 64 + col;
      feat[(size_t)gseg * 2048 + gcol] = f2bf(sum * (1.f / 30.f));
    }
    CFENCE();
    __builtin_amdgcn_s_barrier();
  }
#undef STAGE
}

// ---------------------------------------------------------------------------
// 128x128 kernel: GEMM2 (MODE 2) and the no-workspace fallback (MODE 0).
// MODE 1/2 use XOR-swizzled LDS (chunk^row&7, BK=64 -> 8 chunks/row).
// ---------------------------------------------------------------------------
#define BM 128
#define BN 128
#define BK 64

template<int MODE>
__global__ __launch_bounds__(256, 2)
void gemm_bt(const void* __restrict__ Ap, const void* __restrict__ Bp,
             void* __restrict__ Cp, int Mv, int Nv, int K, int mstep) {
  constexpr int LDK = (MODE == 0) ? 72 : 64;
  __shared__ __align__(16) unsigned short smem[2 * BM * LDK];
  unsigned short* As = smem;
  unsigned short* Bs = smem + BM * LDK;
  float* Cs = (float*)smem;

  const int tid = threadIdx.x;
  const int lane = tid & 63;
  const int w = tid >> 6;
  const int wr = w >> 1, wc = w & 1;
  const int bm0 = blockIdx.y * mstep;
  const int bn0 = blockIdx.x * BN;

  f32x4 acc[4][4];
#pragma unroll
  for (int i = 0; i < 4; ++i)
#pragma unroll
    for (int j = 0; j < 4; ++j) acc[i][j] = (f32x4){0.f, 0.f, 0.f, 0.f};

  const int fr = lane & 15;
  const int ko = (lane >> 4) * 8;

  for (int kt = 0; kt < K; kt += BK) {
    __syncthreads();
    if constexpr (MODE == 0) {
      const float* A = (const float*)Ap;
      const float* B = (const float*)Bp;
      const int r0 = tid >> 4, kq = tid & 15;
#pragma unroll
      for (int i = 0; i < 8; ++i) {
        int row = i * 16 + r0;
        {
          int gm = bm0 + row;
          f32x4 v = {0.f, 0.f, 0.f, 0.f};
          if (gm < Mv) v = *(const f32x4*)(A + (size_t)gm * K + kt + kq * 4);
          *(unsigned long long*)(As + row * LDK + kq * 4) = pack4(v);
        }
        {
          int gn = bn0 + row;
          f32x4 v = {0.f, 0.f, 0.f, 0.f};
          if (gn < Nv) v = *(const f32x4*)(B + (size_t)gn * K + kt + kq * 4);
          *(unsigned long long*)(Bs + row * LDK + kq * 4) = pack4(v);
        }
      }
    } else {
      const unsigned short* A = (const unsigned short*)Ap;
      const unsigned short* B = (const unsigned short*)Bp;
      const int rsub = lane >> 3;
      // pre-swizzle global k: c_log = (lane&7) ^ ((row)&7), row&7 = lane>>3
      const int k8 = (((lane & 7) ^ (lane >> 3)) * 8);
#pragma unroll
      for (int j = 0; j < 4; ++j) {
        int g = w * 4 + j;
        int row = g * 8 + rsub;
        int gm = bm0 + row; if (gm >= Mv) gm = Mv - 1;
        gload_lds16(A + (size_t)gm * K + kt + k8, As + g * 512);
        int gn = bn0 + row; if (gn >= Nv) gn = Nv - 1;
        gload_lds16(B + (size_t)gn * K + kt + k8, Bs + g * 512);
      }
    }
    __syncthreads();
#pragma unroll
    for (int kk = 0; kk < 2; ++kk) {
      // chunk index within row: q2 = kk*4 + (lane>>4); swizzle ^= fr&7
      const int coffA = (MODE == 0) ? (kk * 32 + ko)
                                    : ((((kk << 2) | (lane >> 4)) ^ (fr & 7)) * 8);
      short8 af[4], bfr[4];
#pragma unroll
      for (int i = 0; i < 4; ++i)
        af[i] = *(const short8*)(As + (wr * 64 + i * 16 + fr) * LDK + coffA);
#pragma unroll
      for (int i = 0; i < 4; ++i)
        bfr[i] = *(const short8*)(Bs + (wc * 64 + i * 16 + fr) * LDK + coffA);
#pragma unroll
      for (int i = 0; i < 4; ++i)
#pragma unroll
        for (int j = 0; j < 4; ++j)
          acc[i][j] = __builtin_amdgcn_mfma_f32_16x16x32_bf16(af[i], bfr[j], acc[i][j], 0, 0, 0);
    }
  }
  __syncthreads();

  if constexpr (MODE != 2) {
    unsigned short* feat = (unsigned short*)Cp;
    const int cr0 = (lane >> 4) * 4;
#pragma unroll
    for (int half = 0; half < 2; ++half) {
      if (wc == half) {
#pragma unroll
        for (int i = 0; i < 4; ++i)
#pragma unroll
          for (int j = 0; j < 4; ++j)
#pragma unroll
            for (int r = 0; r < 4; ++r)
              Cs[(wr * 64 + i * 16 + cr0 + r) * 64 + j * 16 + fr] =
                  fmaxf(acc[i][j][r], 0.f);
      }
      __syncthreads();
      {
        int col = tid & 63;
        int s = tid >> 6;
        float sum = 0.f;
#pragma unroll
        for (int r = 0; r < 30; ++r) sum += Cs[(s * 30 + r) * 64 + col];
        int gseg = blockIdx.y * 4 + s;
        int gcol = bn0 + half * 64 + col;
        feat[(size_t)gseg * 2048 + gcol] = f2bf(sum * (1.f / 30.f));
      }
      __syncthreads();
    }
  } else {
    float* out = (float*)Cp;
    const int cr0 = (lane >> 4) * 4;
#pragma unroll
    for (int i = 0; i < 4; ++i)
#pragma unroll
      for (int j = 0; j < 4; ++j)
#pragma unroll
        for (int r = 0; r < 4; ++r) {
          int gm = bm0 + wr * 64 + i * 16 + cr0 + r;
          int gn = bn0 + wc * 64 + j * 16 + fr;
          if (gm < Mv && gn < Nv) out[(size_t)gm * Nv + gn] = acc[i][j][r];
        }
  }
}

extern "C" void kernel_launch(void* const* d_in, const int* in_sizes, int n_in,
                              void* d_out, int out_size, void* d_ws, size_t ws_size,
                              hipStream_t stream) {
  const float* x    = (const float*)d_in[0];
  const float* W1   = (const float*)d_in[2];
  const float* Wlin = (const float*)d_in[4];
  float* out = (float*)d_out;

  const int T = 60000, DIN = 1024, E = 2048, C = 1000, S = 2000;
  char* ws = (char*)d_ws;
  const size_t off_feat = 0;
  const size_t off_wsum = (size_t)S * E * 2;
  const size_t off_w1b  = off_wsum + (size_t)C * E * 2;
  const size_t off_xb   = off_w1b + (size_t)E * DIN * 2;
  const size_t need_full = off_xb + (size_t)T * DIN * 2;   // ~139.4 MB

  unsigned short* feat = (unsigned short*)(ws + off_feat);
  unsigned short* wsum = (unsigned short*)(ws + off_wsum);

  prep_wsum<<<dim3((C * E / 4 + 255) / 256), dim3(256), 0, stream>>>(Wlin, wsum);

  if (ws_size >= need_full) {
    unsigned short* w1b = (unsigned short*)(ws + off_w1b);
    unsigned short* xb  = (unsigned short*)(ws + off_xb);
    int nx4 = T * DIN / 4;
    cvt_f32_bf16<<<dim3((nx4 + 255) / 256), dim3(256), 0, stream>>>(x, xb, nx4);
    int nw4 = E * DIN / 4;
    cvt_f32_bf16<<<dim3((nw4 + 255) / 256), dim3(256), 0, stream>>>(W1, w1b, nw4);
    gemm256_pool<<<dim3(8, 250), dim3(512), 0, stream>>>(xb, w1b, feat, T, DIN);
  } else {
    gemm_bt<0><<<dim3(16, 500), dim3(256), 0, stream>>>(x, W1, feat, T, E, DIN, 120);
  }

  gemm_bt<2><<<dim3(8, 16), dim3(256), 0, stream>>>(feat, wsum, out, S, C, E, 128);
}